// Round 1
// baseline (5279.429 us; speedup 1.0000x reference)
//
#include <hip/hip_runtime.h>
#include <hip/hip_bf16.h>

namespace {

__device__ __forceinline__ float bf2f(unsigned short h) {
    return __uint_as_float(((unsigned int)h) << 16);
}
__device__ __forceinline__ unsigned short f2bf(float f) {
    __hip_bfloat16 h = __float2bfloat16(f);
    return *reinterpret_cast<unsigned short*>(&h);
}

enum { ASRC_F32 = 0, ASRC_MIX = 1, ASRC_BF16 = 2 };
enum { ACT_NONE = 0, ACT_TANH = 1 };
enum { EPI_NONE = 0, EPI_KSCALE = 1, EPI_ADDVEC = 2 };
enum { BL_NT = 0, BL_NN = 1 };

// C[m,n] = sum_k A[m,k] * B(k,n); BL_NT: B stored [n,K] (row n contiguous in k);
// BL_NN: B stored [K,n] (row k contiguous in n).
template <int ASRC, int BLAY, int ACT, int EPI, int SBF>
__launch_bounds__(256) __global__
void gemm_k(int M, int N, int K,
            const float* __restrict__ Af32, const unsigned short* __restrict__ Abf,
            const float* __restrict__ xin, const float* __restrict__ xla,
            const float* __restrict__ mux,
            const float* __restrict__ Bm,
            float* __restrict__ Cf, unsigned short* __restrict__ Cb,
            const float* __restrict__ epi)
{
    __shared__ float As[16][68];
    __shared__ float Bs[16][68];
    const int tid = threadIdx.x;
    const int m0 = blockIdx.y << 6;
    const int n0 = blockIdx.x << 6;
    const int tx = tid & 15, ty = tid >> 4;

    float acc[4][4];
#pragma unroll
    for (int i = 0; i < 4; ++i)
#pragma unroll
        for (int j = 0; j < 4; ++j) acc[i][j] = 0.f;

    const int aml = tid >> 2, akv = (tid & 3) << 2;

    for (int k0 = 0; k0 < K; k0 += 16) {
        float4 a4;
        {
            const size_t off = (size_t)(m0 + aml) * K + (k0 + akv);
            if constexpr (ASRC == ASRC_F32) {
                a4 = *(const float4*)(Af32 + off);
            } else if constexpr (ASRC == ASRC_MIX) {
                const float4 xv = *(const float4*)(xin + off);
                const float4 xl = *(const float4*)(xla + off);
                const float4 mu = *(const float4*)(mux + k0 + akv);
                a4.x = xv.x + (xl.x - xv.x) * mu.x;
                a4.y = xv.y + (xl.y - xv.y) * mu.y;
                a4.z = xv.z + (xl.z - xv.z) * mu.z;
                a4.w = xv.w + (xl.w - xv.w) * mu.w;
            } else {
                const ushort4 u4 = *(const ushort4*)(Abf + off);
                a4.x = bf2f(u4.x); a4.y = bf2f(u4.y);
                a4.z = bf2f(u4.z); a4.w = bf2f(u4.w);
            }
        }
        float4 b4 = make_float4(0.f, 0.f, 0.f, 0.f);
        if constexpr (BLAY == BL_NT) {
            const int bnl = tid >> 2, bkv = (tid & 3) << 2;
            if (n0 + bnl < N)
                b4 = *(const float4*)(Bm + (size_t)(n0 + bnl) * K + (k0 + bkv));
        } else {
            const int bkl = tid >> 4, bnv = (tid & 15) << 2;
            if (n0 + bnv < N)
                b4 = *(const float4*)(Bm + (size_t)(k0 + bkl) * N + (n0 + bnv));
        }
        __syncthreads();  // previous iteration's LDS reads must be done
        As[akv + 0][aml] = a4.x;
        As[akv + 1][aml] = a4.y;
        As[akv + 2][aml] = a4.z;
        As[akv + 3][aml] = a4.w;
        if constexpr (BLAY == BL_NT) {
            const int bnl = tid >> 2, bkv = (tid & 3) << 2;
            Bs[bkv + 0][bnl] = b4.x;
            Bs[bkv + 1][bnl] = b4.y;
            Bs[bkv + 2][bnl] = b4.z;
            Bs[bkv + 3][bnl] = b4.w;
        } else {
            const int bkl = tid >> 4, bnv = (tid & 15) << 2;
            *(float4*)&Bs[bkl][bnv] = b4;
        }
        __syncthreads();
#pragma unroll
        for (int kk = 0; kk < 16; ++kk) {
            const float4 av = *(const float4*)&As[kk][ty << 2];
            const float4 bv = *(const float4*)&Bs[kk][tx << 2];
            const float a_[4] = {av.x, av.y, av.z, av.w};
            const float b_[4] = {bv.x, bv.y, bv.z, bv.w};
#pragma unroll
            for (int i = 0; i < 4; ++i)
#pragma unroll
                for (int j = 0; j < 4; ++j)
                    acc[i][j] = fmaf(a_[i], b_[j], acc[i][j]);
        }
    }

#pragma unroll
    for (int i = 0; i < 4; ++i) {
        const int row = m0 + (ty << 2) + i;
#pragma unroll
        for (int j = 0; j < 4; ++j) {
            const int col = n0 + (tx << 2) + j;
            if (col >= N) continue;
            float v = acc[i][j];
            if constexpr (ACT == ACT_TANH) v = tanhf(v);
            if constexpr (EPI == EPI_KSCALE)
                v *= __expf(fminf(epi[(size_t)row * N + col], 0.f));
            if constexpr (EPI == EPI_ADDVEC) v += epi[col];
            if constexpr (SBF) Cb[(size_t)row * N + col] = f2bf(v);
            else               Cf[(size_t)row * N + col] = v;
        }
    }
}

// xdd[f][m,c] = x[m,c] + (x_last-x)[m,c] * (lambda[f,c] + sum_kk t1flat[f*524288+m*32+kk]*B_lora[f,kk,c])
__launch_bounds__(256) __global__
void xdd_k(const float* __restrict__ x, const float* __restrict__ xla,
           const float* __restrict__ t1, const float* __restrict__ blora,
           const float* __restrict__ lam, float* __restrict__ out, int f)
{
    __shared__ float sh[4][32];
    const int tid = threadIdx.x;
    const int m0 = blockIdx.x << 2;
    if (tid < 128) {
        const int r = tid >> 5, kk = tid & 31;
        sh[r][kk] = t1[(size_t)f * 524288 + (size_t)(m0 + r) * 32 + kk];
    }
    __syncthreads();
    const int c0 = tid << 2;
    const float* bl = blora + f * 32768 + c0;
    float dot[4][4];
#pragma unroll
    for (int r = 0; r < 4; ++r)
#pragma unroll
        for (int j = 0; j < 4; ++j) dot[r][j] = 0.f;
    for (int kk = 0; kk < 32; ++kk) {
        const float4 b4 = *(const float4*)(bl + (size_t)kk * 1024);
#pragma unroll
        for (int r = 0; r < 4; ++r) {
            const float tv = sh[r][kk];
            dot[r][0] = fmaf(tv, b4.x, dot[r][0]);
            dot[r][1] = fmaf(tv, b4.y, dot[r][1]);
            dot[r][2] = fmaf(tv, b4.z, dot[r][2]);
            dot[r][3] = fmaf(tv, b4.w, dot[r][3]);
        }
    }
    const float4 l4 = *(const float4*)(lam + f * 1024 + c0);
#pragma unroll
    for (int r = 0; r < 4; ++r) {
        const size_t idx = (size_t)(m0 + r) * 1024 + c0;
        const float4 xv = *(const float4*)(x + idx);
        const float4 xl = *(const float4*)(xla + idx);
        float4 o;
        o.x = xv.x + (xl.x - xv.x) * (l4.x + dot[r][0]);
        o.y = xv.y + (xl.y - xv.y) * (l4.y + dot[r][1]);
        o.z = xv.z + (xl.z - xv.z) * (l4.z + dot[r][2]);
        o.w = xv.w + (xl.w - xv.w) * (l4.w + dot[r][3]);
        *(float4*)(out + idx) = o;
    }
}

// WKV6: block = (b*H+h, j-half). Thread i holds state rows j in [jbase,jbase+32) for column i.
// y decomposes exactly over j (including the u-term r_j*u_j*k_j*v_i); partials summed in gn_k.
__launch_bounds__(64) __global__
void wkv_k(const unsigned short* __restrict__ r, const unsigned short* __restrict__ k,
           const unsigned short* __restrict__ v, const float* __restrict__ w,
           const float* __restrict__ u, const float* __restrict__ s_in,
           float* __restrict__ y0, float* __restrict__ y1, float* __restrict__ s_out)
{
    const int bh = blockIdx.x >> 1;
    const int jh = blockIdx.x & 1;
    const int b = bh >> 4, h = bh & 15;
    const int i = threadIdx.x;
    const int jbase = jh << 5;
    float* __restrict__ yp = jh ? y1 : y0;

    float s[32];
    const size_t sb = (size_t)bh * 4096;
#pragma unroll
    for (int jj = 0; jj < 32; ++jj) s[jj] = s_in[sb + (size_t)(jbase + jj) * 64 + i];
    const float ui = u[(h << 6) + i];

    __shared__ float4 sh[2][64];
    size_t idx = (size_t)b * 2048 * 1024 + (h << 6) + i;
    int buf = 0;
    for (int t = 0; t < 2048; ++t) {
        const float ri = bf2f(r[idx]);
        const float ki = bf2f(k[idx]);
        const float vi = bf2f(v[idx]);
        const float di = __expf(-__expf(w[idx]));
        sh[buf][i] = make_float4(ri, ki, di, ri * ki * ui);
        __syncthreads();
        float yv = 0.f;
#pragma unroll
        for (int jj = 0; jj < 32; ++jj) {
            const float4 t4 = sh[buf][jbase + jj];
            const float sj = s[jj];
            yv = fmaf(t4.x, sj, yv);      // r_j * s[j,i]
            yv = fmaf(t4.w, vi, yv);      // (r_j u_j k_j) * v_i
            s[jj] = fmaf(t4.z, sj, t4.y * vi);  // d_j*s + k_j*v_i
        }
        yp[idx] = yv;
        buf ^= 1;
        idx += 1024;
    }
#pragma unroll
    for (int jj = 0; jj < 32; ++jj) s_out[sb + (size_t)(jbase + jj) * 64 + i] = s[jj];
}

// GroupNorm over heads of 64 ch (eps = 1e-5*16), then *g, store bf16 z.
__launch_bounds__(256) __global__
void gn_k(const float* __restrict__ y0, const float* __restrict__ y1,
          const unsigned short* __restrict__ g, const float* __restrict__ gam,
          const float* __restrict__ bet, unsigned short* __restrict__ z)
{
    const int tid = threadIdx.x;
    const size_t row = blockIdx.x;
    const int c0 = tid << 2;
    const size_t idx = row * 1024 + c0;
    const float4 a = *(const float4*)(y0 + idx);
    const float4 b = *(const float4*)(y1 + idx);
    const float yv0 = a.x + b.x, yv1 = a.y + b.y, yv2 = a.z + b.z, yv3 = a.w + b.w;
    float s = yv0 + yv1 + yv2 + yv3;
    float q = yv0 * yv0 + yv1 * yv1 + yv2 * yv2 + yv3 * yv3;
#pragma unroll
    for (int off = 1; off < 16; off <<= 1) {
        s += __shfl_xor(s, off, 64);
        q += __shfl_xor(q, off, 64);
    }
    const float mean = s * (1.f / 64.f);
    const float var = q * (1.f / 64.f) - mean * mean;
    const float rstd = rsqrtf(var + 1.6e-4f);
    const float4 gm = *(const float4*)(gam + c0);
    const float4 bt = *(const float4*)(bet + c0);
    const ushort4 gg = *(const ushort4*)(g + idx);
    ushort4 o;
    o.x = f2bf(((yv0 - mean) * rstd * gm.x + bt.x) * bf2f(gg.x));
    o.y = f2bf(((yv1 - mean) * rstd * gm.y + bt.y) * bf2f(gg.y));
    o.z = f2bf(((yv2 - mean) * rstd * gm.z + bt.z) * bf2f(gg.z));
    o.w = f2bf(((yv3 - mean) * rstd * gm.w + bt.w) * bf2f(gg.w));
    *(ushort4*)(z + idx) = o;
}

__launch_bounds__(256) __global__
void copy_k(const float4* __restrict__ src, float4* __restrict__ dst)
{
    const size_t i = (size_t)blockIdx.x * 256 + threadIdx.x;
    dst[i] = src[i];
}

}  // namespace

extern "C" void kernel_launch(void* const* d_in, const int* in_sizes, int n_in,
                              void* d_out, int out_size, void* d_ws, size_t ws_size,
                              hipStream_t stream)
{
    (void)in_sizes; (void)n_in; (void)out_size; (void)ws_size;
    const float* x     = (const float*)d_in[0];
    const float* xla   = (const float*)d_in[1];
    const float* s_in  = (const float*)d_in[2];
    const float* mux   = (const float*)d_in[3];
    const float* lam   = (const float*)d_in[4];
    const float* Amat  = (const float*)d_in[5];
    const float* blora = (const float*)d_in[6];
    const float* tdmu  = (const float*)d_in[7];
    const float* tdA   = (const float*)d_in[8];
    const float* tdB   = (const float*)d_in[9];
    const float* u     = (const float*)d_in[10];
    const float* Wk    = (const float*)d_in[11];
    const float* Wv    = (const float*)d_in[12];
    const float* Wr    = (const float*)d_in[13];
    const float* Wo    = (const float*)d_in[14];
    const float* Wg1   = (const float*)d_in[15];
    const float* Wg2   = (const float*)d_in[16];
    const float* gam   = (const float*)d_in[17];
    const float* bet   = (const float*)d_in[18];

    float* out  = (float*)d_out;          // also w-scratch until final GEMM
    float* xraw = out + 16777216;         // also y-partial scratch until final copy
    float* snew = out + 2 * 16777216;

    char* ws = (char*)d_ws;
    float* x0buf          = (float*)(ws);                 // 64 MB (xdd scratch; later y1)
    float* t1             = (float*)(ws + 67108864);      // 10 MB
    float* tmp            = (float*)(ws + 77594624);      // 10 MB
    unsigned short* kbuf  = (unsigned short*)(ws + 88080384);   // 32 MB (later z)
    unsigned short* vbuf  = (unsigned short*)(ws + 121634816);  // 32 MB
    unsigned short* rbuf  = (unsigned short*)(ws + 155189248);  // 32 MB
    unsigned short* gbuf  = (unsigned short*)(ws + 188743680);  // 32 MB  (total 212 MB)

    float* w  = out;
    float* y0 = xraw;
    float* y1 = x0buf;

    // 1) t1 = tanh(mix(x) @ A)   (16384 x 160, K=1024)
    gemm_k<ASRC_MIX, BL_NN, ACT_TANH, EPI_NONE, 0><<<dim3(3, 256), 256, 0, stream>>>(
        16384, 160, 1024, nullptr, nullptr, x, xla, mux, Amat, t1, nullptr, nullptr);

    // f=0 (w-path): w = tdmu + tanh(w0 @ td_A) @ td_B
    xdd_k<<<4096, 256, 0, stream>>>(x, xla, t1, blora, lam, x0buf, 0);
    gemm_k<ASRC_F32, BL_NN, ACT_TANH, EPI_NONE, 0><<<dim3(1, 256), 256, 0, stream>>>(
        16384, 64, 1024, x0buf, nullptr, nullptr, nullptr, nullptr, tdA, tmp, nullptr, nullptr);
    gemm_k<ASRC_F32, BL_NN, ACT_NONE, EPI_ADDVEC, 0><<<dim3(16, 256), 256, 0, stream>>>(
        16384, 1024, 64, tmp, nullptr, nullptr, nullptr, nullptr, tdB, w, nullptr, tdmu);

    // f=1: k = (k0 @ Wk^T) * exp(min(w,0))  -> bf16
    xdd_k<<<4096, 256, 0, stream>>>(x, xla, t1, blora, lam, x0buf, 1);
    gemm_k<ASRC_F32, BL_NT, ACT_NONE, EPI_KSCALE, 1><<<dim3(16, 256), 256, 0, stream>>>(
        16384, 1024, 1024, x0buf, nullptr, nullptr, nullptr, nullptr, Wk, nullptr, kbuf, w);

    // f=2: v -> bf16
    xdd_k<<<4096, 256, 0, stream>>>(x, xla, t1, blora, lam, x0buf, 2);
    gemm_k<ASRC_F32, BL_NT, ACT_NONE, EPI_NONE, 1><<<dim3(16, 256), 256, 0, stream>>>(
        16384, 1024, 1024, x0buf, nullptr, nullptr, nullptr, nullptr, Wv, nullptr, vbuf, nullptr);

    // f=3: r -> bf16
    xdd_k<<<4096, 256, 0, stream>>>(x, xla, t1, blora, lam, x0buf, 3);
    gemm_k<ASRC_F32, BL_NT, ACT_NONE, EPI_NONE, 1><<<dim3(16, 256), 256, 0, stream>>>(
        16384, 1024, 1024, x0buf, nullptr, nullptr, nullptr, nullptr, Wr, nullptr, rbuf, nullptr);

    // f=4: g = tanh(g0 @ Wg1) @ Wg2 -> bf16
    xdd_k<<<4096, 256, 0, stream>>>(x, xla, t1, blora, lam, x0buf, 4);
    gemm_k<ASRC_F32, BL_NN, ACT_TANH, EPI_NONE, 0><<<dim3(3, 256), 256, 0, stream>>>(
        16384, 160, 1024, x0buf, nullptr, nullptr, nullptr, nullptr, Wg1, tmp, nullptr, nullptr);
    gemm_k<ASRC_F32, BL_NN, ACT_NONE, EPI_NONE, 1><<<dim3(16, 256), 256, 0, stream>>>(
        16384, 1024, 160, tmp, nullptr, nullptr, nullptr, nullptr, Wg2, nullptr, gbuf, nullptr);

    // WKV scan: y partials + final state
    wkv_k<<<256, 64, 0, stream>>>(rbuf, kbuf, vbuf, w, u, s_in, y0, y1, snew);

    // GroupNorm(y0+y1)*g -> z (bf16, reuses kbuf)
    gn_k<<<16384, 256, 0, stream>>>(y0, y1, gbuf, gam, bet, kbuf);

    // out = z @ Wo^T (overwrites w scratch with the real output)
    gemm_k<ASRC_BF16, BL_NT, ACT_NONE, EPI_NONE, 0><<<dim3(16, 256), 256, 0, stream>>>(
        16384, 1024, 1024, nullptr, kbuf, nullptr, nullptr, nullptr, Wo, out, nullptr, nullptr);

    // x_raw = x (after y0 region is consumed)
    copy_k<<<16384, 256, 0, stream>>>((const float4*)x, (float4*)xraw);
}

// Round 2
// 2105.014 us; speedup vs baseline: 2.5080x; 2.5080x over previous
//
#include <hip/hip_runtime.h>
#include <hip/hip_bf16.h>

namespace {

typedef __attribute__((ext_vector_type(8))) short short8x;
typedef __attribute__((ext_vector_type(4))) float f32x4;

__device__ __forceinline__ float bf2f(unsigned short h) {
    return __uint_as_float(((unsigned int)h) << 16);
}
__device__ __forceinline__ unsigned short f2bf(float f) {
    __hip_bfloat16 h = __float2bfloat16(f);
    return *reinterpret_cast<unsigned short*>(&h);
}

enum { ACT_NONE = 0, ACT_TANH = 1 };
enum { EPI_NONE = 0, EPI_KSCALE = 1, EPI_ADDVEC = 2 };

// ---------------- bf16 MFMA GEMM: C[m,n] = sum_k A[m,k]*B[n,k] -----------------
// A: M x K bf16 row-major (M=16384). B: Npad x K bf16 row-major (padded w/ zeros).
// 128x128 tile, 256 threads (4 waves, 2x2 of 64x64), BK=32, one 16x16x32 MFMA
// per 16x16 tile per k-iter. LDS XOR-swizzled (chunk ^= (row>>1)&3) -> 2-way max.
template <int ACT, int EPI, int SBF>
__launch_bounds__(256) __global__
void gemm_mfma(int Npad, int K, int Nreal, int Cstride,
               const unsigned short* __restrict__ A,
               const unsigned short* __restrict__ B,
               float* __restrict__ Cf, unsigned short* __restrict__ Cb,
               const float* __restrict__ epi)
{
    __shared__ unsigned short as_[128 * 32];
    __shared__ unsigned short bs_[128 * 32];
    const int tid = threadIdx.x;
    const int lane = tid & 63;
    const int wave = tid >> 6;
    const int m0 = blockIdx.y << 7;
    const int n0 = blockIdx.x << 7;
    const int wm = (wave >> 1) << 6;
    const int wn = (wave & 1) << 6;

    f32x4 acc[4][4];
    const f32x4 zero = {0.f, 0.f, 0.f, 0.f};
#pragma unroll
    for (int i = 0; i < 4; ++i)
#pragma unroll
        for (int j = 0; j < 4; ++j) acc[i][j] = zero;

    const int sr = tid >> 2;       // row within 64-row chunk
    const int sc4 = tid & 3;       // 8-elt chunk within 32-wide row

    for (int k0 = 0; k0 < K; k0 += 32) {
        const uint4 a0 = *(const uint4*)(A + (size_t)(m0 + sr) * K + k0 + sc4 * 8);
        const uint4 a1 = *(const uint4*)(A + (size_t)(m0 + 64 + sr) * K + k0 + sc4 * 8);
        const uint4 b0 = *(const uint4*)(B + (size_t)(n0 + sr) * K + k0 + sc4 * 8);
        const uint4 b1 = *(const uint4*)(B + (size_t)(n0 + 64 + sr) * K + k0 + sc4 * 8);
        __syncthreads();  // previous iter's LDS reads done
        {
            int r = sr, p = sc4 ^ ((r >> 1) & 3);
            *(uint4*)&as_[r * 32 + p * 8] = a0;
            *(uint4*)&bs_[r * 32 + p * 8] = b0;
            r = 64 + sr; p = sc4 ^ ((r >> 1) & 3);
            *(uint4*)&as_[r * 32 + p * 8] = a1;
            *(uint4*)&bs_[r * 32 + p * 8] = b1;
        }
        __syncthreads();
        const int q = lane >> 4;
        const int l15 = lane & 15;
        short8x af[4], bfr[4];
#pragma unroll
        for (int i = 0; i < 4; ++i) {
            const int m = wm + (i << 4) + l15;
            const int pa = q ^ ((m >> 1) & 3);
            af[i] = *(const short8x*)&as_[m * 32 + pa * 8];
            const int n = wn + (i << 4) + l15;
            const int pb = q ^ ((n >> 1) & 3);
            bfr[i] = *(const short8x*)&bs_[n * 32 + pb * 8];
        }
#pragma unroll
        for (int i = 0; i < 4; ++i)
#pragma unroll
            for (int j = 0; j < 4; ++j)
                acc[i][j] = __builtin_amdgcn_mfma_f32_16x16x32_bf16(af[i], bfr[j], acc[i][j], 0, 0, 0);
    }

    const int q = lane >> 4;
    const int cn = lane & 15;
#pragma unroll
    for (int i = 0; i < 4; ++i) {
#pragma unroll
        for (int j = 0; j < 4; ++j) {
#pragma unroll
            for (int rr = 0; rr < 4; ++rr) {
                const int row = m0 + wm + (i << 4) + (q << 2) + rr;
                const int col = n0 + wn + (j << 4) + cn;
                if (col >= Nreal) continue;
                float v = acc[i][j][rr];
                if constexpr (ACT == ACT_TANH) v = tanhf(v);
                if constexpr (EPI == EPI_KSCALE)
                    v *= __expf(fminf(epi[(size_t)row * 1024 + col], 0.f));
                if constexpr (EPI == EPI_ADDVEC) v += epi[col];
                if constexpr (SBF) Cb[(size_t)row * Cstride + col] = f2bf(v);
                else               Cf[(size_t)row * Cstride + col] = v;
            }
        }
    }
}

// mix[m,c] = bf16(x + (x_last - x) * miu_x[c])
__launch_bounds__(256) __global__
void mix_k(const float* __restrict__ x, const float* __restrict__ xla,
           const float* __restrict__ mux, unsigned short* __restrict__ out)
{
    const size_t idx = ((size_t)blockIdx.x * 256 + threadIdx.x) * 4;
    const int c = (int)(idx & 1023);
    const float4 xv = *(const float4*)(x + idx);
    const float4 xl = *(const float4*)(xla + idx);
    const float4 mu = *(const float4*)(mux + c);
    ushort4 o;
    o.x = f2bf(xv.x + (xl.x - xv.x) * mu.x);
    o.y = f2bf(xv.y + (xl.y - xv.y) * mu.y);
    o.z = f2bf(xv.z + (xl.z - xv.z) * mu.z);
    o.w = f2bf(xv.w + (xl.w - xv.w) * mu.w);
    *(ushort4*)(out + idx) = o;
}

// plain fp32 -> bf16 convert (n mult of 1024; grid = n/1024)
__launch_bounds__(256) __global__
void convert_k(const float* __restrict__ src, unsigned short* __restrict__ dst)
{
    const size_t idx = ((size_t)blockIdx.x * 256 + threadIdx.x) * 4;
    const float4 v = *(const float4*)(src + idx);
    ushort4 o;
    o.x = f2bf(v.x); o.y = f2bf(v.y); o.z = f2bf(v.z); o.w = f2bf(v.w);
    *(ushort4*)(dst + idx) = o;
}

// dst[n*K + k] = (n < Nsrc) ? bf16(src[k*Nsrc + n]) : 0   (grid.y = Npad rows)
__launch_bounds__(256) __global__
void transpose_k(const float* __restrict__ src, unsigned short* __restrict__ dst,
                 int K, int Nsrc)
{
    const int k = blockIdx.x * 256 + threadIdx.x;
    const int n = blockIdx.y;
    if (k < K)
        dst[(size_t)n * K + k] = (n < Nsrc) ? f2bf(src[(size_t)k * Nsrc + n]) : (unsigned short)0;
}

// xdd[f][m,c] = x + (x_last-x) * (lambda[f,c] + sum_kk t1flat[f*524288+m*32+kk]*B_lora[f,kk,c])
__launch_bounds__(256) __global__
void xdd_k(const float* __restrict__ x, const float* __restrict__ xla,
           const unsigned short* __restrict__ t1, const float* __restrict__ blora,
           const float* __restrict__ lam, unsigned short* __restrict__ out, int f)
{
    __shared__ float sh[4][32];
    const int tid = threadIdx.x;
    const int m0 = blockIdx.x << 2;
    if (tid < 128) {
        const int r = tid >> 5, kk = tid & 31;
        sh[r][kk] = bf2f(t1[(size_t)f * 524288 + (size_t)(m0 + r) * 32 + kk]);
    }
    __syncthreads();
    const int c0 = tid << 2;
    const float* bl = blora + f * 32768 + c0;
    float dot[4][4];
#pragma unroll
    for (int r = 0; r < 4; ++r)
#pragma unroll
        for (int j = 0; j < 4; ++j) dot[r][j] = 0.f;
    for (int kk = 0; kk < 32; ++kk) {
        const float4 b4 = *(const float4*)(bl + (size_t)kk * 1024);
#pragma unroll
        for (int r = 0; r < 4; ++r) {
            const float tv = sh[r][kk];
            dot[r][0] = fmaf(tv, b4.x, dot[r][0]);
            dot[r][1] = fmaf(tv, b4.y, dot[r][1]);
            dot[r][2] = fmaf(tv, b4.z, dot[r][2]);
            dot[r][3] = fmaf(tv, b4.w, dot[r][3]);
        }
    }
    const float4 l4 = *(const float4*)(lam + f * 1024 + c0);
#pragma unroll
    for (int r = 0; r < 4; ++r) {
        const size_t idx = (size_t)(m0 + r) * 1024 + c0;
        const float4 xv = *(const float4*)(x + idx);
        const float4 xl = *(const float4*)(xla + idx);
        ushort4 o;
        o.x = f2bf(xv.x + (xl.x - xv.x) * (l4.x + dot[r][0]));
        o.y = f2bf(xv.y + (xl.y - xv.y) * (l4.y + dot[r][1]));
        o.z = f2bf(xv.z + (xl.z - xv.z) * (l4.z + dot[r][2]));
        o.w = f2bf(xv.w + (xl.w - xv.w) * (l4.w + dot[r][3]));
        *(ushort4*)(out + idx) = o;
    }
}

// WKV6 scan. Block = (bh, j-half): single wave of 64 threads; thread i holds
// state rows [jbase, jbase+32) for value-column i. No __syncthreads (wave-
// synchronous LDS broadcast); r/k/v/w prefetched 8 steps ahead, double-buffered.
#define WKV_PROC(RR, KK, VV, WW, CIDX)                                        \
    do {                                                                      \
        _Pragma("unroll")                                                     \
        for (int tt = 0; tt < 8; ++tt) {                                      \
            const float ri = bf2f(RR[tt]);                                    \
            const float ki = bf2f(KK[tt]);                                    \
            const float vi = bf2f(VV[tt]);                                    \
            const float di = __expf(-__expf(WW[tt]));                         \
            sh[i] = make_float4(ri, ki, di, ri * ki * ui);                    \
            __builtin_amdgcn_wave_barrier();                                  \
            float yv = 0.f;                                                   \
            _Pragma("unroll")                                                 \
            for (int jj = 0; jj < 32; ++jj) {                                 \
                const float4 t4 = sh[jbase + jj];                             \
                const float sj = s[jj];                                       \
                yv = fmaf(t4.x, sj, yv);                                      \
                yv = fmaf(t4.w, vi, yv);                                      \
                s[jj] = fmaf(t4.z, sj, t4.y * vi);                            \
            }                                                                 \
            yp[base + (size_t)((CIDX) * 8 + tt) * 1024] = yv;                 \
            __builtin_amdgcn_wave_barrier();                                  \
        }                                                                     \
    } while (0)

__launch_bounds__(64) __global__
void wkv_k(const unsigned short* __restrict__ r, const unsigned short* __restrict__ k,
           const unsigned short* __restrict__ v, const float* __restrict__ w,
           const float* __restrict__ u, const float* __restrict__ s_in,
           float* __restrict__ y0, float* __restrict__ y1, float* __restrict__ s_out)
{
    const int bh = blockIdx.x >> 1;
    const int jh = blockIdx.x & 1;
    const int h = bh & 15;
    const int i = threadIdx.x;
    const int jbase = jh << 5;
    float* __restrict__ yp = jh ? y1 : y0;

    float s[32];
    const size_t sb = (size_t)bh * 4096;
#pragma unroll
    for (int jj = 0; jj < 32; ++jj) s[jj] = s_in[sb + (size_t)(jbase + jj) * 64 + i];
    const float ui = u[(h << 6) + i];

    __shared__ float4 sh[64];
    const size_t base = (size_t)(bh >> 4) * 2048 * 1024 + (h << 6) + i;

    unsigned short ra[8], ka[8], va[8]; float wa[8];
    unsigned short rb[8], kb[8], vb[8]; float wb[8];

#pragma unroll
    for (int tt = 0; tt < 8; ++tt) {
        const size_t id = base + (size_t)tt * 1024;
        ra[tt] = r[id]; ka[tt] = k[id]; va[tt] = v[id]; wa[tt] = w[id];
    }
    for (int c = 0; c < 256; c += 2) {
        {
            const size_t cb_ = base + (size_t)(c + 1) * 8192;
#pragma unroll
            for (int tt = 0; tt < 8; ++tt) {
                const size_t id = cb_ + (size_t)tt * 1024;
                rb[tt] = r[id]; kb[tt] = k[id]; vb[tt] = v[id]; wb[tt] = w[id];
            }
        }
        WKV_PROC(ra, ka, va, wa, c);
        if (c + 2 < 256) {
            const size_t ca_ = base + (size_t)(c + 2) * 8192;
#pragma unroll
            for (int tt = 0; tt < 8; ++tt) {
                const size_t id = ca_ + (size_t)tt * 1024;
                ra[tt] = r[id]; ka[tt] = k[id]; va[tt] = v[id]; wa[tt] = w[id];
            }
        }
        WKV_PROC(rb, kb, vb, wb, c + 1);
    }
#pragma unroll
    for (int jj = 0; jj < 32; ++jj) s_out[sb + (size_t)(jbase + jj) * 64 + i] = s[jj];
}

// GroupNorm over heads of 64 ch (eps = 1e-5*16), then *g, store bf16 z.
__launch_bounds__(256) __global__
void gn_k(const float* __restrict__ y0, const float* __restrict__ y1,
          const unsigned short* __restrict__ g, const float* __restrict__ gam,
          const float* __restrict__ bet, unsigned short* __restrict__ z)
{
    const int tid = threadIdx.x;
    const size_t row = blockIdx.x;
    const int c0 = tid << 2;
    const size_t idx = row * 1024 + c0;
    const float4 a = *(const float4*)(y0 + idx);
    const float4 b = *(const float4*)(y1 + idx);
    const float yv0 = a.x + b.x, yv1 = a.y + b.y, yv2 = a.z + b.z, yv3 = a.w + b.w;
    float sm = yv0 + yv1 + yv2 + yv3;
    float q = yv0 * yv0 + yv1 * yv1 + yv2 * yv2 + yv3 * yv3;
#pragma unroll
    for (int off = 1; off < 16; off <<= 1) {
        sm += __shfl_xor(sm, off, 64);
        q += __shfl_xor(q, off, 64);
    }
    const float mean = sm * (1.f / 64.f);
    const float var = q * (1.f / 64.f) - mean * mean;
    const float rstd = rsqrtf(var + 1.6e-4f);
    const float4 gm = *(const float4*)(gam + c0);
    const float4 bt = *(const float4*)(bet + c0);
    const ushort4 gg = *(const ushort4*)(g + idx);
    ushort4 o;
    o.x = f2bf(((yv0 - mean) * rstd * gm.x + bt.x) * bf2f(gg.x));
    o.y = f2bf(((yv1 - mean) * rstd * gm.y + bt.y) * bf2f(gg.y));
    o.z = f2bf(((yv2 - mean) * rstd * gm.z + bt.z) * bf2f(gg.z));
    o.w = f2bf(((yv3 - mean) * rstd * gm.w + bt.w) * bf2f(gg.w));
    *(ushort4*)(z + idx) = o;
}

__launch_bounds__(256) __global__
void copy_k(const float4* __restrict__ src, float4* __restrict__ dst)
{
    const size_t i = (size_t)blockIdx.x * 256 + threadIdx.x;
    dst[i] = src[i];
}

}  // namespace

extern "C" void kernel_launch(void* const* d_in, const int* in_sizes, int n_in,
                              void* d_out, int out_size, void* d_ws, size_t ws_size,
                              hipStream_t stream)
{
    (void)in_sizes; (void)n_in; (void)out_size; (void)ws_size;
    const float* x     = (const float*)d_in[0];
    const float* xla   = (const float*)d_in[1];
    const float* s_in  = (const float*)d_in[2];
    const float* mux   = (const float*)d_in[3];
    const float* lam   = (const float*)d_in[4];
    const float* Amat  = (const float*)d_in[5];
    const float* blora = (const float*)d_in[6];
    const float* tdmu  = (const float*)d_in[7];
    const float* tdA   = (const float*)d_in[8];
    const float* tdB   = (const float*)d_in[9];
    const float* u     = (const float*)d_in[10];
    const float* Wk    = (const float*)d_in[11];
    const float* Wv    = (const float*)d_in[12];
    const float* Wr    = (const float*)d_in[13];
    const float* Wo    = (const float*)d_in[14];
    const float* Wg1   = (const float*)d_in[15];
    const float* Wg2   = (const float*)d_in[16];
    const float* gam   = (const float*)d_in[17];
    const float* bet   = (const float*)d_in[18];

    float* out  = (float*)d_out;          // w-scratch until final GEMM
    float* xraw = out + 16777216;         // y0 scratch until final copy
    float* snew = out + 2 * 16777216;

    char* ws = (char*)d_ws;
    unsigned short* mixb   = (unsigned short*)(ws);              // 32 MB (dead after G1)
    unsigned short* xddb   = (unsigned short*)(ws + 33554432);   // 32 MB (dead after G7)
    unsigned short* t1     = (unsigned short*)(ws + 67108864);   // 5.25 MB
    unsigned short* tanh64 = (unsigned short*)(ws + 72351744);   // 2 MB
    unsigned short* tanhg  = (unsigned short*)(ws + 74448896);   // 5.25 MB
    unsigned short* kbuf   = (unsigned short*)(ws + 79691776);   // 32 MB (-> z after wkv)
    unsigned short* vbuf   = (unsigned short*)(ws + 113246208);  // 32 MB
    unsigned short* rbuf   = (unsigned short*)(ws + 146800640);  // 32 MB
    unsigned short* gbuf   = (unsigned short*)(ws + 180355072);  // 32 MB
    unsigned short* wkt    = (unsigned short*)(ws + 213909504);  // 2 MB
    unsigned short* wvt    = (unsigned short*)(ws + 216006656);
    unsigned short* wrt    = (unsigned short*)(ws + 218103808);
    unsigned short* wot    = (unsigned short*)(ws + 220200960);
    unsigned short* at_    = (unsigned short*)(ws + 222298112);  // 256x1024
    unsigned short* tdat   = (unsigned short*)(ws + 222822400);  // 128x1024
    unsigned short* tdbt   = (unsigned short*)(ws + 223084544);  // 1024x64
    unsigned short* wg1t   = (unsigned short*)(ws + 223215616);  // 256x1024
    unsigned short* wg2t   = (unsigned short*)(ws + 223739904);  // 1024x160 (end ~224 MB)

    float* w  = out;            // 16384x1024 fp32
    float* y0 = xraw;           // fp32 partial (j-half 0)
    float* y1 = (float*)ws;     // fp32 partial over dead mix+xdd regions

    // --- weight conversions ---
    convert_k<<<1024, 256, 0, stream>>>(Wk, wkt);
    convert_k<<<1024, 256, 0, stream>>>(Wv, wvt);
    convert_k<<<1024, 256, 0, stream>>>(Wr, wrt);
    convert_k<<<1024, 256, 0, stream>>>(Wo, wot);
    transpose_k<<<dim3(4, 256), 256, 0, stream>>>(Amat, at_, 1024, 160);
    transpose_k<<<dim3(4, 128), 256, 0, stream>>>(tdA, tdat, 1024, 64);
    transpose_k<<<dim3(1, 1024), 256, 0, stream>>>(tdB, tdbt, 64, 1024);
    transpose_k<<<dim3(4, 256), 256, 0, stream>>>(Wg1, wg1t, 1024, 160);
    transpose_k<<<dim3(1, 1024), 256, 0, stream>>>(Wg2, wg2t, 160, 1024);

    // --- G1: t1 = tanh(mix @ A)  (N=160 pad 256, K=1024) ---
    mix_k<<<16384, 256, 0, stream>>>(x, xla, mux, mixb);
    gemm_mfma<ACT_TANH, EPI_NONE, 1><<<dim3(2, 128), 256, 0, stream>>>(
        256, 1024, 160, 160, mixb, at_, nullptr, t1, nullptr);

    // --- f=0: w = tdmu + tanh(w0 @ tdA) @ tdB ---
    xdd_k<<<4096, 256, 0, stream>>>(x, xla, t1, blora, lam, xddb, 0);
    gemm_mfma<ACT_TANH, EPI_NONE, 1><<<dim3(1, 128), 256, 0, stream>>>(
        128, 1024, 64, 64, xddb, tdat, nullptr, tanh64, nullptr);
    gemm_mfma<ACT_NONE, EPI_ADDVEC, 0><<<dim3(8, 128), 256, 0, stream>>>(
        1024, 64, 1024, 1024, tanh64, tdbt, w, nullptr, tdmu);

    // --- f=1: k = (k0 @ Wk^T) * exp(min(w,0)) -> bf16 ---
    xdd_k<<<4096, 256, 0, stream>>>(x, xla, t1, blora, lam, xddb, 1);
    gemm_mfma<ACT_NONE, EPI_KSCALE, 1><<<dim3(8, 128), 256, 0, stream>>>(
        1024, 1024, 1024, 1024, xddb, wkt, nullptr, kbuf, w);

    // --- f=2: v ---
    xdd_k<<<4096, 256, 0, stream>>>(x, xla, t1, blora, lam, xddb, 2);
    gemm_mfma<ACT_NONE, EPI_NONE, 1><<<dim3(8, 128), 256, 0, stream>>>(
        1024, 1024, 1024, 1024, xddb, wvt, nullptr, vbuf, nullptr);

    // --- f=3: r ---
    xdd_k<<<4096, 256, 0, stream>>>(x, xla, t1, blora, lam, xddb, 3);
    gemm_mfma<ACT_NONE, EPI_NONE, 1><<<dim3(8, 128), 256, 0, stream>>>(
        1024, 1024, 1024, 1024, xddb, wrt, nullptr, rbuf, nullptr);

    // --- f=4: g = tanh(g0 @ Wg1) @ Wg2 ---
    xdd_k<<<4096, 256, 0, stream>>>(x, xla, t1, blora, lam, xddb, 4);
    gemm_mfma<ACT_TANH, EPI_NONE, 1><<<dim3(2, 128), 256, 0, stream>>>(
        256, 1024, 160, 160, xddb, wg1t, nullptr, tanhg, nullptr);
    gemm_mfma<ACT_NONE, EPI_NONE, 1><<<dim3(8, 128), 256, 0, stream>>>(
        1024, 160, 1024, 1024, tanhg, wg2t, nullptr, gbuf, nullptr);

    // --- WKV scan ---
    wkv_k<<<256, 64, 0, stream>>>(rbuf, kbuf, vbuf, w, u, s_in, y0, y1, snew);

    // --- GroupNorm(y0+y1)*g -> z (reuses kbuf) ---
    gn_k<<<16384, 256, 0, stream>>>(y0, y1, gbuf, gam, bet, kbuf);

    // --- out = z @ Wo^T (fp32, overwrites w scratch) ---
    gemm_mfma<ACT_NONE, EPI_NONE, 0><<<dim3(8, 128), 256, 0, stream>>>(
        1024, 1024, 1024, 1024, kbuf, wot, out, nullptr, nullptr);

    // --- x_raw = x ---
    copy_k<<<16384, 256, 0, stream>>>((const float4*)x, (float4*)xraw);
}